// Round 3
// baseline (890.884 us; speedup 1.0000x reference)
//
#include <hip/hip_runtime.h>

#define NG 20000
#define NC 50000
#define NT 8000
#define EGC 600000
#define EGT 200000
#define NREP 8

// ---------------- CSR build: pass A (count + position, 8-way replicated) ----------------

struct SegA { const int* src; const int* dst; int ne; int* pos; int* ci_rep; int* co_rep; int ns, nd; };

static __device__ void countpos_body(const SegA& s, int i, int r) {
    int d = s.dst[i];
    s.pos[i] = atomicAdd(&s.ci_rep[r * s.nd + d], 1);
    atomicAdd(&s.co_rep[r * s.ns + s.src[i]], 1);
}

static __global__ __launch_bounds__(256)
void countpos4_kernel(SegA a, SegA b, SegA c, SegA d) {
    int r = blockIdx.x & (NREP - 1);
    int i = blockIdx.x * 256 + threadIdx.x;
    if (i < a.ne) { countpos_body(a, i, r); return; }
    i -= a.ne;
    if (i < b.ne) { countpos_body(b, i, r); return; }
    i -= b.ne;
    if (i < c.ne) { countpos_body(c, i, r); return; }
    i -= c.ne;
    if (i < d.ne) { countpos_body(d, i, r); }
}

// ---------------- scales + replica prefix (turns ci_rep into per-bin exclusive prefixes) ----

struct SPSeg { int* ci_rep; int* co_rep; float* so; float* si; int* ci_tot; int ns, nd, len; };

static __device__ void sp_body(const SPSeg& s, int i) {
    if (i < s.ns) {
        int c = 0;
#pragma unroll
        for (int r = 0; r < NREP; ++r) c += s.co_rep[r * s.ns + i];
        if (c < 1) c = 1;
        s.so[i] = 1.0f / sqrtf((float)c);
    }
    if (i < s.nd) {
        int run = 0;
#pragma unroll
        for (int r = 0; r < NREP; ++r) {
            int t = s.ci_rep[r * s.nd + i];
            s.ci_rep[r * s.nd + i] = run;
            run += t;
        }
        s.ci_tot[i] = run;
        int c = run < 1 ? 1 : run;
        s.si[i] = 1.0f / sqrtf((float)c);
    }
}

static __global__ __launch_bounds__(256)
void spscales4_kernel(SPSeg a, SPSeg b, SPSeg c, SPSeg d) {
    int i = blockIdx.x * 256 + threadIdx.x;
    if (i < a.len) { sp_body(a, i); return; }
    i -= a.len;
    if (i < b.len) { sp_body(b, i); return; }
    i -= b.len;
    if (i < c.len) { sp_body(c, i); return; }
    i -= c.len;
    if (i < d.len) { sp_body(d, i); }
}

// ---------------- tiled block scan (1024 threads, shfl + LDS + carry) ----------------

static __device__ void scan_body(const int* __restrict__ cnt, int* __restrict__ off, int n) {
    __shared__ int wsum[16];
    __shared__ int carry_s, total_s;
    const int t = threadIdx.x;
    const int lane = t & 63, wid = t >> 6;
    if (t == 0) carry_s = 0;
    __syncthreads();
    for (int base = 0; base < n; base += 1024) {
        int i = base + t;
        int v = (i < n) ? cnt[i] : 0;
        int x = v;
#pragma unroll
        for (int d = 1; d < 64; d <<= 1) {
            int y = __shfl_up(x, d, 64);
            if (lane >= d) x += y;
        }
        if (lane == 63) wsum[wid] = x;
        __syncthreads();
        if (wid == 0) {
            int w = (lane < 16) ? wsum[lane] : 0;
            int xx = w;
#pragma unroll
            for (int d = 1; d < 16; d <<= 1) {
                int y = __shfl_up(xx, d, 64);
                if (lane >= d) xx += y;
            }
            if (lane < 16) wsum[lane] = xx - w;
            if (lane == 15) total_s = xx;
        }
        __syncthreads();
        int carry = carry_s;
        if (i < n) off[i] = carry + wsum[wid] + (x - v);
        __syncthreads();
        if (t == 0) carry_s = carry + total_s;
        __syncthreads();
    }
    if (t == 0) off[n] = carry_s;
}

static __global__ __launch_bounds__(1024)
void scan4_kernel(const int* c0, int* o0, int n0,
                  const int* c1, int* o1, int n1,
                  const int* c2, int* o2, int n2,
                  const int* c3, int* o3, int n3) {
    if (blockIdx.x == 0) scan_body(c0, o0, n0);
    else if (blockIdx.x == 1) scan_body(c1, o1, n1);
    else if (blockIdx.x == 2) scan_body(c2, o2, n2);
    else scan_body(c3, o3, n3);
}

// ---------------- CSR build: pass B (atomic-free scatter) ----------------

struct SegB { const int* src; const int* dst; int ne; const int* pos; const int* ci_rep; const int* off; int* eid; int nd; };

static __device__ void scatter_body(const SegB& s, int i, int r) {
    int d = s.dst[i];
    s.eid[s.off[d] + s.ci_rep[r * s.nd + d] + s.pos[i]] = s.src[i];
}

static __global__ __launch_bounds__(256)
void scatter4_kernel(SegB a, SegB b, SegB c, SegB d) {
    int r = blockIdx.x & (NREP - 1);
    int i = blockIdx.x * 256 + threadIdx.x;
    if (i < a.ne) { scatter_body(a, i, r); return; }
    i -= a.ne;
    if (i < b.ne) { scatter_body(b, i, r); return; }
    i -= b.ne;
    if (i < c.ne) { scatter_body(c, i, r); return; }
    i -= c.ne;
    if (i < d.ne) { scatter_body(d, i, r); }
}

// ---------------- dense GEMM: out[n,128] = opt_relu((X * rs) @ W + bias) ----------------

template<int RELU>
static __global__ __launch_bounds__(256)
void gemm_kernel(const float* __restrict__ X, const float* __restrict__ rs,
                 const float* __restrict__ W, const float* __restrict__ bias,
                 float* __restrict__ out, int n) {
    __shared__ float xs[32][128];
    const int r0 = blockIdx.x * 32;
    const int t = threadIdx.x;
    for (int i = t; i < 1024; i += 256) {
        int r = i >> 5;
        int c4 = i & 31;
        int row = r0 + r;
        float4 v = make_float4(0.f, 0.f, 0.f, 0.f);
        if (row < n) {
            v = reinterpret_cast<const float4*>(X)[row * 32 + c4];
            if (rs) { float s = rs[row]; v.x *= s; v.y *= s; v.z *= s; v.w *= s; }
        }
        reinterpret_cast<float4*>(&xs[r][0])[c4] = v;
    }
    __syncthreads();
    const int tx = t & 31, ty = t >> 5;
    const int c0 = tx << 2;
    float acc[4][4] = {};
    const float* wp = W + c0;
    for (int k = 0; k < 128; k += 4) {
        float4 w0 = *reinterpret_cast<const float4*>(wp + (k + 0) * 128);
        float4 w1 = *reinterpret_cast<const float4*>(wp + (k + 1) * 128);
        float4 w2 = *reinterpret_cast<const float4*>(wp + (k + 2) * 128);
        float4 w3 = *reinterpret_cast<const float4*>(wp + (k + 3) * 128);
#pragma unroll
        for (int i = 0; i < 4; ++i) {
            float4 xv = *reinterpret_cast<const float4*>(&xs[ty * 4 + i][k]);
            acc[i][0] += xv.x * w0.x; acc[i][1] += xv.x * w0.y; acc[i][2] += xv.x * w0.z; acc[i][3] += xv.x * w0.w;
            acc[i][0] += xv.y * w1.x; acc[i][1] += xv.y * w1.y; acc[i][2] += xv.y * w1.z; acc[i][3] += xv.y * w1.w;
            acc[i][0] += xv.z * w2.x; acc[i][1] += xv.z * w2.y; acc[i][2] += xv.z * w2.z; acc[i][3] += xv.z * w2.w;
            acc[i][0] += xv.w * w3.x; acc[i][1] += xv.w * w3.y; acc[i][2] += xv.w * w3.z; acc[i][3] += xv.w * w3.w;
        }
    }
    float4 bv = make_float4(0.f, 0.f, 0.f, 0.f);
    if (bias) bv = reinterpret_cast<const float4*>(bias)[tx];
#pragma unroll
    for (int i = 0; i < 4; ++i) {
        int row = r0 + ty * 4 + i;
        if (row < n) {
            float4 o;
            o.x = acc[i][0] + bv.x; o.y = acc[i][1] + bv.y;
            o.z = acc[i][2] + bv.z; o.w = acc[i][3] + bv.w;
            if (RELU) {
                o.x = fmaxf(o.x, 0.f); o.y = fmaxf(o.y, 0.f);
                o.z = fmaxf(o.z, 0.f); o.w = fmaxf(o.w, 0.f);
            }
            reinterpret_cast<float4*>(out)[row * 32 + tx] = o;
        }
    }
}

// ---------------- column-sliced CSR aggregation ----------------
// Slice = SLICE columns (SLICE*4 bytes per row) so the per-slice source working
// set (n_src*SLICE*4 B) fits a 4 MiB per-XCD L2. Slice index is the slow part of
// blockIdx.x so slices are roughly time-serialized.
// MODE 0: out = sum( h[eid]*pre )            (pre optional)
// MODE 1: out = relu(si*sum + b) * post      (post optional)
// MODE 2: out += relu(si*sum + b)

template<int MODE, int SLICE>
static __global__ __launch_bounds__(256)
void agg_kernel(const float* __restrict__ h, const float* __restrict__ pre,
                const int* __restrict__ off, const int* __restrict__ eid,
                const float* __restrict__ si, const float* __restrict__ bias,
                const float* __restrict__ post,
                float* __restrict__ out, int n_dst) {
    constexpr int RPB = 256 / SLICE;
    const int bps = (n_dst + RPB - 1) / RPB;
    const int slice = blockIdx.x / bps;
    const int brow = blockIdx.x % bps;
    const int row = brow * RPB + (int)(threadIdx.x / SLICE);
    const int col = slice * SLICE + (int)(threadIdx.x % SLICE);
    if (row >= n_dst) return;
    int e0 = off[row], e1 = off[row + 1];
    float acc = 0.f;
    int j = e0;
    for (; j + 4 <= e1; j += 4) {
        int s0 = eid[j], s1 = eid[j + 1], s2 = eid[j + 2], s3 = eid[j + 3];
        float v0 = h[s0 * 128 + col];
        float v1 = h[s1 * 128 + col];
        float v2 = h[s2 * 128 + col];
        float v3 = h[s3 * 128 + col];
        if (pre) {
            acc += v0 * pre[s0] + v1 * pre[s1] + v2 * pre[s2] + v3 * pre[s3];
        } else {
            acc += v0 + v1 + v2 + v3;
        }
    }
    for (; j < e1; ++j) {
        int s = eid[j];
        float v = h[s * 128 + col];
        acc += pre ? v * pre[s] : v;
    }
    float* o = out + row * 128 + col;
    if (MODE == 0) {
        *o = acc;
    } else {
        float v = fmaxf(acc * si[row] + bias[col], 0.f);
        if (MODE == 1 && post) v *= post[row];
        if (MODE == 2) v += *o;
        *o = v;
    }
}

// ---------------- orchestration ----------------

extern "C" void kernel_launch(void* const* d_in, const int* in_sizes, int n_in,
                              void* d_out, int out_size, void* d_ws, size_t ws_size,
                              hipStream_t stream) {
    const float* x_cell   = (const float*)d_in[1];
    const float* x_gotem  = (const float*)d_in[2];
    const float* W_eg_c2g = (const float*)d_in[3];  const float* b_eg_c2g = (const float*)d_in[4];
    const float* W_eg_t2g = (const float*)d_in[5];  const float* b_eg_t2g = (const float*)d_in[6];
    const float* W1_g2c   = (const float*)d_in[11]; const float* b1_g2c   = (const float*)d_in[12];
    const float* W1_g2t   = (const float*)d_in[15]; const float* b1_g2t   = (const float*)d_in[16];
    const float* W2_c2g   = (const float*)d_in[21]; const float* b2_c2g   = (const float*)d_in[22];
    const float* W2_t2g   = (const float*)d_in[25]; const float* b2_t2g   = (const float*)d_in[26];
    const float* W3_g2c   = (const float*)d_in[27]; const float* b3_g2c   = (const float*)d_in[28];
    const float* Wd_cell  = (const float*)d_in[29]; const float* bd_cell  = (const float*)d_in[30];
    const int* eg2c_src = (const int*)d_in[31]; const int* eg2c_dst = (const int*)d_in[32];
    const int* ec2g_src = (const int*)d_in[33]; const int* ec2g_dst = (const int*)d_in[34];
    const int* eg2t_src = (const int*)d_in[35]; const int* eg2t_dst = (const int*)d_in[36];
    const int* et2g_src = (const int*)d_in[37]; const int* et2g_dst = (const int*)d_in[38];

    char* p = (char*)d_ws;
    auto alloc = [&](size_t bytes) { char* r = p; p += (bytes + 255) & ~(size_t)255; return r; };
    float* h_buf = (float*)alloc((size_t)NC * 128 * 4);
    float* g_buf = (float*)alloc((size_t)NG * 128 * 4);
    float* c_buf = (float*)alloc((size_t)NC * 128 * 4);
    float* t_buf = (float*)alloc((size_t)NT * 128 * 4);
    int* off_gc = (int*)alloc((NG + 1) * 4);  int* eid_gc = (int*)alloc((size_t)EGC * 4); // ec2g (dst=gene)
    int* off_gt = (int*)alloc((NG + 1) * 4);  int* eid_gt = (int*)alloc((size_t)EGT * 4); // et2g (dst=gene)
    int* off_c  = (int*)alloc((NC + 1) * 4);  int* eid_c  = (int*)alloc((size_t)EGC * 4); // eg2c (dst=cell)
    int* off_t  = (int*)alloc((NT + 1) * 4);  int* eid_t  = (int*)alloc((size_t)EGT * 4); // eg2t (dst=gotem)
    float* so_ec2g = (float*)alloc(NC * 4);
    float* so_et2g = (float*)alloc(NT * 4);
    float* so_eg2c = (float*)alloc(NG * 4);
    float* so_eg2t = (float*)alloc(NG * 4);
    float* si_ec2g = (float*)alloc(NG * 4);
    float* si_et2g = (float*)alloc(NG * 4);
    float* si_eg2c = (float*)alloc(NC * 4);
    float* si_eg2t = (float*)alloc(NT * 4);
    int* ct_a = (int*)alloc(NG * 4);
    int* ct_b = (int*)alloc(NG * 4);
    int* ct_c = (int*)alloc(NC * 4);
    int* ct_d = (int*)alloc(NT * 4);
    int* pos_a = (int*)alloc((size_t)EGC * 4);
    int* pos_b = (int*)alloc((size_t)EGT * 4);
    int* pos_c = (int*)alloc((size_t)EGC * 4);
    int* pos_d = (int*)alloc((size_t)EGT * 4);
    char* z0 = alloc(0);
    int* cia = (int*)alloc((size_t)NREP * NG * 4); int* coa = (int*)alloc((size_t)NREP * NC * 4);
    int* cib = (int*)alloc((size_t)NREP * NG * 4); int* cob = (int*)alloc((size_t)NREP * NT * 4);
    int* cic = (int*)alloc((size_t)NREP * NC * 4); int* coc = (int*)alloc((size_t)NREP * NG * 4);
    int* cid = (int*)alloc((size_t)NREP * NT * 4); int* cod = (int*)alloc((size_t)NREP * NG * 4);
    size_t zbytes = (size_t)(p - z0);
    hipMemsetAsync(z0, 0, zbytes, stream);

    auto cdiv = [](int a, int b) { return (a + b - 1) / b; };
    const int ETOT = 2 * EGC + 2 * EGT;

    // ---- CSR build ----
    SegA aa{ec2g_src, ec2g_dst, EGC, pos_a, cia, coa, NC, NG};
    SegA ab{et2g_src, et2g_dst, EGT, pos_b, cib, cob, NT, NG};
    SegA ac{eg2c_src, eg2c_dst, EGC, pos_c, cic, coc, NG, NC};
    SegA ad{eg2t_src, eg2t_dst, EGT, pos_d, cid, cod, NG, NT};
    countpos4_kernel<<<cdiv(ETOT, 256), 256, 0, stream>>>(aa, ab, ac, ad);

    SPSeg sa{cia, coa, so_ec2g, si_ec2g, ct_a, NC, NG, NC};
    SPSeg sb{cib, cob, so_et2g, si_et2g, ct_b, NT, NG, NG};
    SPSeg sc{cic, coc, so_eg2c, si_eg2c, ct_c, NG, NC, NC};
    SPSeg sd{cid, cod, so_eg2t, si_eg2t, ct_d, NG, NT, NG};
    spscales4_kernel<<<cdiv(NC + NG + NC + NG, 256), 256, 0, stream>>>(sa, sb, sc, sd);

    scan4_kernel<<<4, 1024, 0, stream>>>(ct_a, off_gc, NG, ct_b, off_gt, NG,
                                         ct_c, off_c, NC, ct_d, off_t, NT);

    SegB ba{ec2g_src, ec2g_dst, EGC, pos_a, cia, off_gc, eid_gc, NG};
    SegB bb{et2g_src, et2g_dst, EGT, pos_b, cib, off_gt, eid_gt, NG};
    SegB bc{eg2c_src, eg2c_dst, EGC, pos_c, cic, off_c, eid_c, NC};
    SegB bd{eg2t_src, eg2t_dst, EGT, pos_d, cid, off_t, eid_t, NT};
    scatter4_kernel<<<cdiv(ETOT, 256), 256, 0, stream>>>(ba, bb, bc, bd);

    // grid sizes for sliced aggs
    auto agg_grid = [&](int n_dst, int SL) { return cdiv(n_dst, 256 / SL) * (128 / SL); };

    // ---- Layer E: g = relu(gconv(x_cell via ec2g) + gconv(x_gotem via et2g)) ----
    // part A agg-first: A = sum(x_cell*so) ; g = relu(si*(A@W) + b). src ws: NC*64B=3.2MB -> SLICE16
    agg_kernel<0, 16><<<agg_grid(NG, 16), 256, 0, stream>>>(x_cell, so_ec2g, off_gc, eid_gc, nullptr, nullptr, nullptr, h_buf, NG);
    gemm_kernel<1><<<cdiv(NG, 32), 256, 0, stream>>>(h_buf, si_ec2g, W_eg_c2g, b_eg_c2g, g_buf, NG);
    // part B gemm-first: h = (x_gotem*so)@W ; g += relu(si*agg + b). src ws: NT*128B=1MB -> SLICE32
    gemm_kernel<0><<<cdiv(NT, 32), 256, 0, stream>>>(x_gotem, so_et2g, W_eg_t2g, nullptr, h_buf, NT);
    agg_kernel<2, 32><<<agg_grid(NG, 32), 256, 0, stream>>>(h_buf, nullptr, off_gt, eid_gt, si_et2g, b_eg_t2g, nullptr, g_buf, NG);

    // ---- c1 = gconv(g via eg2c), folded post-scale so_ec2g (c1 only feeds g2) ----
    gemm_kernel<0><<<cdiv(NG, 32), 256, 0, stream>>>(g_buf, so_eg2c, W1_g2c, nullptr, h_buf, NG);
    agg_kernel<1, 32><<<agg_grid(NC, 32), 256, 0, stream>>>(h_buf, nullptr, off_c, eid_c, si_eg2c, b1_g2c, so_ec2g, c_buf, NC);

    // ---- t1 = gconv(g via eg2t): agg-first ----
    agg_kernel<0, 32><<<agg_grid(NT, 32), 256, 0, stream>>>(g_buf, so_eg2t, off_t, eid_t, nullptr, nullptr, nullptr, h_buf, NT);
    gemm_kernel<1><<<cdiv(NT, 32), 256, 0, stream>>>(h_buf, si_eg2t, W1_g2t, b1_g2t, t_buf, NT);

    // ---- g2 = gconv(c1 via ec2g) + gconv(t1 via et2g) ----
    agg_kernel<0, 16><<<agg_grid(NG, 16), 256, 0, stream>>>(c_buf, nullptr, off_gc, eid_gc, nullptr, nullptr, nullptr, h_buf, NG);
    gemm_kernel<1><<<cdiv(NG, 32), 256, 0, stream>>>(h_buf, si_ec2g, W2_c2g, b2_c2g, g_buf, NG);
    gemm_kernel<0><<<cdiv(NT, 32), 256, 0, stream>>>(t_buf, so_et2g, W2_t2g, nullptr, h_buf, NT);
    agg_kernel<2, 32><<<agg_grid(NG, 32), 256, 0, stream>>>(h_buf, nullptr, off_gt, eid_gt, si_et2g, b2_t2g, nullptr, g_buf, NG);

    // ---- c3 = gconv(g2 via eg2c) ----
    gemm_kernel<0><<<cdiv(NG, 32), 256, 0, stream>>>(g_buf, so_eg2c, W3_g2c, nullptr, h_buf, NG);
    agg_kernel<1, 32><<<agg_grid(NC, 32), 256, 0, stream>>>(h_buf, nullptr, off_c, eid_c, si_eg2c, b3_g2c, nullptr, c_buf, NC);

    // ---- out = c3 @ Wd_cell + bd_cell ----
    gemm_kernel<0><<<cdiv(NC, 32), 256, 0, stream>>>(c_buf, nullptr, Wd_cell, bd_cell, (float*)d_out, NC);
}

// Round 7
// 671.501 us; speedup vs baseline: 1.3267x; 1.3267x over previous
//
#include <hip/hip_runtime.h>

#define NG 20000
#define NC 50000
#define NT 8000
#define EGC 600000
#define EGT 200000
#define CHUNK 25000   // edges per histogram block-row (600k/24, 200k/8)

// ---------------- CSR build phase 1: LDS-privatized histograms ----------------
// 12 segments = 4 edge types x {dst, src}, large bin-spaces split into ranges
// of <=12800 bins (<=51.2 KB LDS). Each block owns (row, range): counts its
// 25000-edge chunk into LDS, writes per-edge local pos (dst side only) and its
// replica row. Zero global atomics.

struct HSeg { const int* idx; int* rep; int* pos; int ne, nb, bpr, nranges, nd; };
struct HTab { HSeg s[12]; };

static __global__ __launch_bounds__(1024)
void hist_lds_kernel(HTab tab) {
    __shared__ int h[12800];
    int b = blockIdx.x, sidx = 0;
    for (;;) {
        int nbl = tab.s[sidx].nb * tab.s[sidx].nranges;
        if (b < nbl) break;
        b -= nbl; ++sidx;
    }
    const HSeg g = tab.s[sidx];
    const int row = b % g.nb, range = b / g.nb;
    const int lo = range * g.bpr;
    const int hi = min(lo + g.bpr, g.nd);
    const int nbins = hi - lo;
    for (int i = threadIdx.x; i < nbins; i += 1024) h[i] = 0;
    __syncthreads();
    const int e0 = row * CHUNK;
    const int e1 = min(e0 + CHUNK, g.ne);
    if (g.pos) {
        for (int i = e0 + (int)threadIdx.x; i < e1; i += 1024) {
            int d = g.idx[i];
            if (d >= lo && d < hi) {
                int p = atomicAdd(&h[d - lo], 1);
                g.pos[i] = p;
            }
        }
    } else {
        for (int i = e0 + (int)threadIdx.x; i < e1; i += 1024) {
            int d = g.idx[i];
            if (d >= lo && d < hi) atomicAdd(&h[d - lo], 1);
        }
    }
    __syncthreads();
    int* rp = g.rep + (size_t)row * g.nd + lo;
    for (int i = threadIdx.x; i < nbins; i += 1024) rp[i] = h[i];
}

// ---------------- scales + replica prefix ----------------
// dst side: convert rep rows into per-bin exclusive prefixes over rows, emit
// total count (for scan) + si = deg_in^-1/2. src side: sum rows -> so.

struct SPSeg { int* repd; const int* reps; float* so; float* si; int* ci_tot; int ns, nd, nb, len; };

static __device__ void sp_body(const SPSeg& s, int i) {
    if (i < s.ns) {
        int c = 0;
        for (int r = 0; r < s.nb; ++r) c += s.reps[(size_t)r * s.ns + i];
        if (c < 1) c = 1;
        s.so[i] = 1.0f / sqrtf((float)c);
    }
    if (i < s.nd) {
        int run = 0;
        for (int r = 0; r < s.nb; ++r) {
            int* p = s.repd + (size_t)r * s.nd + i;
            int t = *p; *p = run; run += t;
        }
        s.ci_tot[i] = run;
        int c = run < 1 ? 1 : run;
        s.si[i] = 1.0f / sqrtf((float)c);
    }
}

static __global__ __launch_bounds__(256)
void spscales4_kernel(SPSeg a, SPSeg b, SPSeg c, SPSeg d) {
    int i = blockIdx.x * 256 + threadIdx.x;
    if (i < a.len) { sp_body(a, i); return; }
    i -= a.len;
    if (i < b.len) { sp_body(b, i); return; }
    i -= b.len;
    if (i < c.len) { sp_body(c, i); return; }
    i -= c.len;
    if (i < d.len) { sp_body(d, i); }
}

// ---------------- tiled block scan (1024 threads, shfl + LDS + carry) ----------------

static __device__ void scan_body(const int* __restrict__ cnt, int* __restrict__ off, int n) {
    __shared__ int wsum[16];
    __shared__ int carry_s, total_s;
    const int t = threadIdx.x;
    const int lane = t & 63, wid = t >> 6;
    if (t == 0) carry_s = 0;
    __syncthreads();
    for (int base = 0; base < n; base += 1024) {
        int i = base + t;
        int v = (i < n) ? cnt[i] : 0;
        int x = v;
#pragma unroll
        for (int d = 1; d < 64; d <<= 1) {
            int y = __shfl_up(x, d, 64);
            if (lane >= d) x += y;
        }
        if (lane == 63) wsum[wid] = x;
        __syncthreads();
        if (wid == 0) {
            int w = (lane < 16) ? wsum[lane] : 0;
            int xx = w;
#pragma unroll
            for (int d = 1; d < 16; d <<= 1) {
                int y = __shfl_up(xx, d, 64);
                if (lane >= d) xx += y;
            }
            if (lane < 16) wsum[lane] = xx - w;
            if (lane == 15) total_s = xx;
        }
        __syncthreads();
        int carry = carry_s;
        if (i < n) off[i] = carry + wsum[wid] + (x - v);
        __syncthreads();
        if (t == 0) carry_s = carry + total_s;
        __syncthreads();
    }
    if (t == 0) off[n] = carry_s;
}

static __global__ __launch_bounds__(1024)
void scan4_kernel(const int* c0, int* o0, int n0,
                  const int* c1, int* o1, int n1,
                  const int* c2, int* o2, int n2,
                  const int* c3, int* o3, int n3) {
    if (blockIdx.x == 0) scan_body(c0, o0, n0);
    else if (blockIdx.x == 1) scan_body(c1, o1, n1);
    else if (blockIdx.x == 2) scan_body(c2, o2, n2);
    else scan_body(c3, o3, n3);
}

// ---------------- CSR build phase 2: atomic-free scatter ----------------

struct SSeg { const int* srce; const int* dste; const int* pos; const int* rep; const int* off; int* eid; int ne, nd; };

static __device__ void scatter_body(const SSeg& s, int i) {
    int row = i / CHUNK;
    int d = s.dste[i];
    s.eid[s.off[d] + s.rep[(size_t)row * s.nd + d] + s.pos[i]] = s.srce[i];
}

static __global__ __launch_bounds__(256)
void scatter4_kernel(SSeg a, SSeg b, SSeg c, SSeg d) {
    int i = blockIdx.x * 256 + threadIdx.x;
    if (i < a.ne) { scatter_body(a, i); return; }
    i -= a.ne;
    if (i < b.ne) { scatter_body(b, i); return; }
    i -= b.ne;
    if (i < c.ne) { scatter_body(c, i); return; }
    i -= c.ne;
    if (i < d.ne) { scatter_body(d, i); }
}

// ---------------- dense GEMM: out[n,128] = opt_relu((X * rs) @ W + bias) ----------------

template<int RELU>
static __global__ __launch_bounds__(256)
void gemm_kernel(const float* __restrict__ X, const float* __restrict__ rs,
                 const float* __restrict__ W, const float* __restrict__ bias,
                 float* __restrict__ out, int n) {
    __shared__ float xs[32][128];
    const int r0 = blockIdx.x * 32;
    const int t = threadIdx.x;
    for (int i = t; i < 1024; i += 256) {
        int r = i >> 5;
        int c4 = i & 31;
        int row = r0 + r;
        float4 v = make_float4(0.f, 0.f, 0.f, 0.f);
        if (row < n) {
            v = reinterpret_cast<const float4*>(X)[row * 32 + c4];
            if (rs) { float s = rs[row]; v.x *= s; v.y *= s; v.z *= s; v.w *= s; }
        }
        reinterpret_cast<float4*>(&xs[r][0])[c4] = v;
    }
    __syncthreads();
    const int tx = t & 31, ty = t >> 5;
    const int c0 = tx << 2;
    float acc[4][4] = {};
    const float* wp = W + c0;
    for (int k = 0; k < 128; k += 4) {
        float4 w0 = *reinterpret_cast<const float4*>(wp + (k + 0) * 128);
        float4 w1 = *reinterpret_cast<const float4*>(wp + (k + 1) * 128);
        float4 w2 = *reinterpret_cast<const float4*>(wp + (k + 2) * 128);
        float4 w3 = *reinterpret_cast<const float4*>(wp + (k + 3) * 128);
#pragma unroll
        for (int i = 0; i < 4; ++i) {
            float4 xv = *reinterpret_cast<const float4*>(&xs[ty * 4 + i][k]);
            acc[i][0] += xv.x * w0.x; acc[i][1] += xv.x * w0.y; acc[i][2] += xv.x * w0.z; acc[i][3] += xv.x * w0.w;
            acc[i][0] += xv.y * w1.x; acc[i][1] += xv.y * w1.y; acc[i][2] += xv.y * w1.z; acc[i][3] += xv.y * w1.w;
            acc[i][0] += xv.z * w2.x; acc[i][1] += xv.z * w2.y; acc[i][2] += xv.z * w2.z; acc[i][3] += xv.z * w2.w;
            acc[i][0] += xv.w * w3.x; acc[i][1] += xv.w * w3.y; acc[i][2] += xv.w * w3.z; acc[i][3] += xv.w * w3.w;
        }
    }
    float4 bv = make_float4(0.f, 0.f, 0.f, 0.f);
    if (bias) bv = reinterpret_cast<const float4*>(bias)[tx];
#pragma unroll
    for (int i = 0; i < 4; ++i) {
        int row = r0 + ty * 4 + i;
        if (row < n) {
            float4 o;
            o.x = acc[i][0] + bv.x; o.y = acc[i][1] + bv.y;
            o.z = acc[i][2] + bv.z; o.w = acc[i][3] + bv.w;
            if (RELU) {
                o.x = fmaxf(o.x, 0.f); o.y = fmaxf(o.y, 0.f);
                o.z = fmaxf(o.z, 0.f); o.w = fmaxf(o.w, 0.f);
            }
            reinterpret_cast<float4*>(out)[row * 32 + tx] = o;
        }
    }
}

// ---------------- CSR aggregation: one wave per dst row (round-2 shape) ----------------
// MODE 0: out = sum( h[eid]*pre )            (pre optional)
// MODE 1: out = relu(si*sum + b) * post      (post optional)
// MODE 2: out += relu(si*sum + b)

template<int MODE>
static __global__ __launch_bounds__(256)
void agg_kernel(const float* __restrict__ h, const float* __restrict__ pre,
                const int* __restrict__ off, const int* __restrict__ eid,
                const float* __restrict__ si, const float* __restrict__ bias,
                const float* __restrict__ post,
                float* __restrict__ out, int n_dst) {
    int row = blockIdx.x * 4 + (threadIdx.x >> 6);
    if (row >= n_dst) return;
    int lane = threadIdx.x & 63;
    int e0 = off[row], e1 = off[row + 1];
    float ax = 0.f, ay = 0.f;
    const float2* h2 = reinterpret_cast<const float2*>(h);
    int j = e0;
    for (; j + 4 <= e1; j += 4) {
        int s0 = eid[j], s1 = eid[j + 1], s2 = eid[j + 2], s3 = eid[j + 3];
        float2 v0 = h2[s0 * 64 + lane];
        float2 v1 = h2[s1 * 64 + lane];
        float2 v2 = h2[s2 * 64 + lane];
        float2 v3 = h2[s3 * 64 + lane];
        if (pre) {
            float p0 = pre[s0], p1 = pre[s1], p2 = pre[s2], p3 = pre[s3];
            ax += v0.x * p0 + v1.x * p1 + v2.x * p2 + v3.x * p3;
            ay += v0.y * p0 + v1.y * p1 + v2.y * p2 + v3.y * p3;
        } else {
            ax += v0.x + v1.x + v2.x + v3.x;
            ay += v0.y + v1.y + v2.y + v3.y;
        }
    }
    for (; j < e1; ++j) {
        int s = eid[j];
        float2 v = h2[s * 64 + lane];
        float pp = pre ? pre[s] : 1.0f;
        ax += v.x * pp; ay += v.y * pp;
    }
    float2* o2 = reinterpret_cast<float2*>(out) + row * 64 + lane;
    if (MODE == 0) {
        *o2 = make_float2(ax, ay);
    } else {
        float s = si[row];
        float2 b = reinterpret_cast<const float2*>(bias)[lane];
        float ox = fmaxf(ax * s + b.x, 0.f);
        float oy = fmaxf(ay * s + b.y, 0.f);
        if (MODE == 1 && post) { float pm = post[row]; ox *= pm; oy *= pm; }
        if (MODE == 2) { float2 cur = *o2; ox += cur.x; oy += cur.y; }
        *o2 = make_float2(ox, oy);
    }
}

// ---------------- orchestration ----------------

extern "C" void kernel_launch(void* const* d_in, const int* in_sizes, int n_in,
                              void* d_out, int out_size, void* d_ws, size_t ws_size,
                              hipStream_t stream) {
    const float* x_cell   = (const float*)d_in[1];
    const float* x_gotem  = (const float*)d_in[2];
    const float* W_eg_c2g = (const float*)d_in[3];  const float* b_eg_c2g = (const float*)d_in[4];
    const float* W_eg_t2g = (const float*)d_in[5];  const float* b_eg_t2g = (const float*)d_in[6];
    const float* W1_g2c   = (const float*)d_in[11]; const float* b1_g2c   = (const float*)d_in[12];
    const float* W1_g2t   = (const float*)d_in[15]; const float* b1_g2t   = (const float*)d_in[16];
    const float* W2_c2g   = (const float*)d_in[21]; const float* b2_c2g   = (const float*)d_in[22];
    const float* W2_t2g   = (const float*)d_in[25]; const float* b2_t2g   = (const float*)d_in[26];
    const float* W3_g2c   = (const float*)d_in[27]; const float* b3_g2c   = (const float*)d_in[28];
    const float* Wd_cell  = (const float*)d_in[29]; const float* bd_cell  = (const float*)d_in[30];
    const int* eg2c_src = (const int*)d_in[31]; const int* eg2c_dst = (const int*)d_in[32];
    const int* ec2g_src = (const int*)d_in[33]; const int* ec2g_dst = (const int*)d_in[34];
    const int* eg2t_src = (const int*)d_in[35]; const int* eg2t_dst = (const int*)d_in[36];
    const int* et2g_src = (const int*)d_in[37]; const int* et2g_dst = (const int*)d_in[38];

    char* p = (char*)d_ws;
    auto alloc = [&](size_t bytes) { char* r = p; p += (bytes + 255) & ~(size_t)255; return r; };
    float* h_buf = (float*)alloc((size_t)NC * 128 * 4);
    float* g_buf = (float*)alloc((size_t)NG * 128 * 4);
    float* c_buf = (float*)alloc((size_t)NC * 128 * 4);
    float* t_buf = (float*)alloc((size_t)NT * 128 * 4);
    int* off_gc = (int*)alloc((NG + 1) * 4);  int* eid_gc = (int*)alloc((size_t)EGC * 4); // ec2g (dst=gene)
    int* off_gt = (int*)alloc((NG + 1) * 4);  int* eid_gt = (int*)alloc((size_t)EGT * 4); // et2g (dst=gene)
    int* off_c  = (int*)alloc((NC + 1) * 4);  int* eid_c  = (int*)alloc((size_t)EGC * 4); // eg2c (dst=cell)
    int* off_t  = (int*)alloc((NT + 1) * 4);  int* eid_t  = (int*)alloc((size_t)EGT * 4); // eg2t (dst=gotem)
    float* so_ec2g = (float*)alloc(NC * 4);
    float* so_et2g = (float*)alloc(NT * 4);
    float* so_eg2c = (float*)alloc(NG * 4);
    float* so_eg2t = (float*)alloc(NG * 4);
    float* si_ec2g = (float*)alloc(NG * 4);
    float* si_et2g = (float*)alloc(NG * 4);
    float* si_eg2c = (float*)alloc(NC * 4);
    float* si_eg2t = (float*)alloc(NT * 4);
    int* ct_a = (int*)alloc(NG * 4);
    int* ct_b = (int*)alloc(NG * 4);
    int* ct_c = (int*)alloc(NC * 4);
    int* ct_d = (int*)alloc(NT * 4);
    int* pos_a = (int*)alloc((size_t)EGC * 4);
    int* pos_b = (int*)alloc((size_t)EGT * 4);
    int* pos_c = (int*)alloc((size_t)EGC * 4);
    int* pos_d = (int*)alloc((size_t)EGT * 4);
    // replica arrays [nb][nd] — dst side (prefix-able) and src side (sum-only)
    int* rd_a = (int*)alloc((size_t)24 * NG * 4);
    int* rd_b = (int*)alloc((size_t)8  * NG * 4);
    int* rd_c = (int*)alloc((size_t)24 * NC * 4);
    int* rd_d = (int*)alloc((size_t)8  * NT * 4);
    int* rs_a = (int*)alloc((size_t)24 * NC * 4);
    int* rs_b = (int*)alloc((size_t)8  * NT * 4);
    int* rs_c = (int*)alloc((size_t)24 * NG * 4);
    int* rs_d = (int*)alloc((size_t)8  * NG * 4);

    auto cdiv = [](int a, int b) { return (a + b - 1) / b; };
    const int ETOT = 2 * EGC + 2 * EGT;

    // ---- phase 1: LDS histograms (12 segs; bpr: NG->10000x2, NC->12500x4, NT->8000x1) ----
    HTab tab;
    tab.s[0]  = {ec2g_dst, rd_a, pos_a, EGC, 24, 10000, 2, NG};
    tab.s[1]  = {et2g_dst, rd_b, pos_b, EGT,  8, 10000, 2, NG};
    tab.s[2]  = {eg2c_dst, rd_c, pos_c, EGC, 24, 12500, 4, NC};
    tab.s[3]  = {eg2t_dst, rd_d, pos_d, EGT,  8,  8000, 1, NT};
    tab.s[4]  = {ec2g_src, rs_a, nullptr, EGC, 24, 12500, 4, NC};
    tab.s[5]  = {et2g_src, rs_b, nullptr, EGT,  8,  8000, 1, NT};
    tab.s[6]  = {eg2c_src, rs_c, nullptr, EGC, 24, 10000, 2, NG};
    tab.s[7]  = {eg2t_src, rs_d, nullptr, EGT,  8, 10000, 2, NG};
    // pad remaining (zero blocks by construction since grid stops first)
    tab.s[8] = tab.s[9] = tab.s[10] = tab.s[11] = HSeg{nullptr, nullptr, nullptr, 0, 0, 1, 0, 0};
    int hist_blocks = 24*2 + 8*2 + 24*4 + 8*1 + 24*4 + 8*1 + 24*2 + 8*2;  // 336
    hist_lds_kernel<<<hist_blocks, 1024, 0, stream>>>(tab);

    // ---- scales + replica prefix ----
    SPSeg sa{rd_a, rs_a, so_ec2g, si_ec2g, ct_a, NC, NG, 24, NC};
    SPSeg sb{rd_b, rs_b, so_et2g, si_et2g, ct_b, NT, NG,  8, NG};
    SPSeg sc{rd_c, rs_c, so_eg2c, si_eg2c, ct_c, NG, NC, 24, NC};
    SPSeg sd{rd_d, rs_d, so_eg2t, si_eg2t, ct_d, NG, NT,  8, NG};
    spscales4_kernel<<<cdiv(NC + NG + NC + NG, 256), 256, 0, stream>>>(sa, sb, sc, sd);

    scan4_kernel<<<4, 1024, 0, stream>>>(ct_a, off_gc, NG, ct_b, off_gt, NG,
                                         ct_c, off_c, NC, ct_d, off_t, NT);

    // ---- phase 2: atomic-free scatter ----
    SSeg ba{ec2g_src, ec2g_dst, pos_a, rd_a, off_gc, eid_gc, EGC, NG};
    SSeg bb{et2g_src, et2g_dst, pos_b, rd_b, off_gt, eid_gt, EGT, NG};
    SSeg bc{eg2c_src, eg2c_dst, pos_c, rd_c, off_c,  eid_c,  EGC, NC};
    SSeg bd{eg2t_src, eg2t_dst, pos_d, rd_d, off_t,  eid_t,  EGT, NT};
    scatter4_kernel<<<cdiv(ETOT, 256), 256, 0, stream>>>(ba, bb, bc, bd);

    // ---- Layer E: g = relu(gconv(x_cell via ec2g) + gconv(x_gotem via et2g)) ----
    agg_kernel<0><<<cdiv(NG, 4), 256, 0, stream>>>(x_cell, so_ec2g, off_gc, eid_gc, nullptr, nullptr, nullptr, h_buf, NG);
    gemm_kernel<1><<<cdiv(NG, 32), 256, 0, stream>>>(h_buf, si_ec2g, W_eg_c2g, b_eg_c2g, g_buf, NG);
    gemm_kernel<0><<<cdiv(NT, 32), 256, 0, stream>>>(x_gotem, so_et2g, W_eg_t2g, nullptr, h_buf, NT);
    agg_kernel<2><<<cdiv(NG, 4), 256, 0, stream>>>(h_buf, nullptr, off_gt, eid_gt, si_et2g, b_eg_t2g, nullptr, g_buf, NG);

    // ---- c1 = gconv(g via eg2c), post-scale fold so_ec2g (c1 only feeds g2) ----
    gemm_kernel<0><<<cdiv(NG, 32), 256, 0, stream>>>(g_buf, so_eg2c, W1_g2c, nullptr, h_buf, NG);
    agg_kernel<1><<<cdiv(NC, 4), 256, 0, stream>>>(h_buf, nullptr, off_c, eid_c, si_eg2c, b1_g2c, so_ec2g, c_buf, NC);

    // ---- t1 = gconv(g via eg2t): agg-first ----
    agg_kernel<0><<<cdiv(NT, 4), 256, 0, stream>>>(g_buf, so_eg2t, off_t, eid_t, nullptr, nullptr, nullptr, h_buf, NT);
    gemm_kernel<1><<<cdiv(NT, 32), 256, 0, stream>>>(h_buf, si_eg2t, W1_g2t, b1_g2t, t_buf, NT);

    // ---- g2 = gconv(c1 via ec2g) + gconv(t1 via et2g) ----
    agg_kernel<0><<<cdiv(NG, 4), 256, 0, stream>>>(c_buf, nullptr, off_gc, eid_gc, nullptr, nullptr, nullptr, h_buf, NG);
    gemm_kernel<1><<<cdiv(NG, 32), 256, 0, stream>>>(h_buf, si_ec2g, W2_c2g, b2_c2g, g_buf, NG);
    gemm_kernel<0><<<cdiv(NT, 32), 256, 0, stream>>>(t_buf, so_et2g, W2_t2g, nullptr, h_buf, NT);
    agg_kernel<2><<<cdiv(NG, 4), 256, 0, stream>>>(h_buf, nullptr, off_gt, eid_gt, si_et2g, b2_t2g, nullptr, g_buf, NG);

    // ---- c3 = gconv(g2 via eg2c) ----
    gemm_kernel<0><<<cdiv(NG, 32), 256, 0, stream>>>(g_buf, so_eg2c, W3_g2c, nullptr, h_buf, NG);
    agg_kernel<1><<<cdiv(NC, 4), 256, 0, stream>>>(h_buf, nullptr, off_c, eid_c, si_eg2c, b3_g2c, nullptr, c_buf, NC);

    // ---- out = c3 @ Wd_cell + bd_cell ----
    gemm_kernel<0><<<cdiv(NC, 32), 256, 0, stream>>>(c_buf, nullptr, Wd_cell, bd_cell, (float*)d_out, NC);
}

// Round 8
// 566.847 us; speedup vs baseline: 1.5716x; 1.1846x over previous
//
#include <hip/hip_runtime.h>
#include <hip/hip_fp16.h>

#define NG 20000
#define NC 50000
#define NT 8000
#define EGC 600000
#define EGT 200000
#define CHUNK 25000   // edges per histogram block-row (600k/24, 200k/8)

// ---------------- CSR build phase 1: LDS-privatized histograms ----------------

struct HSeg { const int* idx; int* rep; int* pos; int ne, nb, bpr, nranges, nd; };
struct HTab { HSeg s[12]; };

static __global__ __launch_bounds__(1024)
void hist_lds_kernel(HTab tab) {
    __shared__ int h[12800];
    int b = blockIdx.x, sidx = 0;
    for (;;) {
        int nbl = tab.s[sidx].nb * tab.s[sidx].nranges;
        if (b < nbl) break;
        b -= nbl; ++sidx;
    }
    const HSeg g = tab.s[sidx];
    const int row = b % g.nb, range = b / g.nb;
    const int lo = range * g.bpr;
    const int hi = min(lo + g.bpr, g.nd);
    const int nbins = hi - lo;
    for (int i = threadIdx.x; i < nbins; i += 1024) h[i] = 0;
    __syncthreads();
    const int e0 = row * CHUNK;
    const int e1 = min(e0 + CHUNK, g.ne);
    if (g.pos) {
        for (int i = e0 + (int)threadIdx.x; i < e1; i += 1024) {
            int d = g.idx[i];
            if (d >= lo && d < hi) {
                int p = atomicAdd(&h[d - lo], 1);
                g.pos[i] = p;
            }
        }
    } else {
        for (int i = e0 + (int)threadIdx.x; i < e1; i += 1024) {
            int d = g.idx[i];
            if (d >= lo && d < hi) atomicAdd(&h[d - lo], 1);
        }
    }
    __syncthreads();
    int* rp = g.rep + (size_t)row * g.nd + lo;
    for (int i = threadIdx.x; i < nbins; i += 1024) rp[i] = h[i];
}

// ---------------- scales + replica prefix ----------------

struct SPSeg { int* repd; const int* reps; float* so; float* si; int* ci_tot; int ns, nd, nb, len; };

static __device__ void sp_body(const SPSeg& s, int i) {
    if (i < s.ns) {
        int c = 0;
        for (int r = 0; r < s.nb; ++r) c += s.reps[(size_t)r * s.ns + i];
        if (c < 1) c = 1;
        s.so[i] = 1.0f / sqrtf((float)c);
    }
    if (i < s.nd) {
        int run = 0;
        for (int r = 0; r < s.nb; ++r) {
            int* p = s.repd + (size_t)r * s.nd + i;
            int t = *p; *p = run; run += t;
        }
        s.ci_tot[i] = run;
        int c = run < 1 ? 1 : run;
        s.si[i] = 1.0f / sqrtf((float)c);
    }
}

static __global__ __launch_bounds__(256)
void spscales4_kernel(SPSeg a, SPSeg b, SPSeg c, SPSeg d) {
    int i = blockIdx.x * 256 + threadIdx.x;
    if (i < a.len) { sp_body(a, i); return; }
    i -= a.len;
    if (i < b.len) { sp_body(b, i); return; }
    i -= b.len;
    if (i < c.len) { sp_body(c, i); return; }
    i -= c.len;
    if (i < d.len) { sp_body(d, i); }
}

// ---------------- x_cell -> fp16 copy with folded so pre-scale ----------------

static __global__ __launch_bounds__(256)
void xconv_kernel(const float* __restrict__ x, const float* __restrict__ so,
                  float2* __restrict__ out) {
    int i = blockIdx.x * 256 + threadIdx.x;    // float4-granule index over NC*32
    if (i >= NC * 32) return;
    int row = i >> 5;
    float s = so[row];
    float4 v = reinterpret_cast<const float4*>(x)[i];
    float2 pk;
    *reinterpret_cast<__half2*>(&pk.x) = __floats2half2_rn(v.x * s, v.y * s);
    *reinterpret_cast<__half2*>(&pk.y) = __floats2half2_rn(v.z * s, v.w * s);
    out[i] = pk;
}

// ---------------- tiled block scan, 8 elems/thread (VPT=8, tile 8192) ----------------

static __device__ void scan_body(const int* __restrict__ cnt, int* __restrict__ off, int n) {
    __shared__ int wsum[16];
    __shared__ int carry_s, total_s;
    const int t = threadIdx.x;
    const int lane = t & 63, wid = t >> 6;
    if (t == 0) carry_s = 0;
    __syncthreads();
    for (int base = 0; base < n; base += 8192) {
        int i0 = base + t * 8;
        int v[8];
        if (i0 + 8 <= n) {
            int4 a = *reinterpret_cast<const int4*>(cnt + i0);
            int4 b = *reinterpret_cast<const int4*>(cnt + i0 + 4);
            v[0]=a.x; v[1]=a.y; v[2]=a.z; v[3]=a.w; v[4]=b.x; v[5]=b.y; v[6]=b.z; v[7]=b.w;
        } else {
#pragma unroll
            for (int k = 0; k < 8; ++k) v[k] = (i0 + k < n) ? cnt[i0 + k] : 0;
        }
        int tsum = 0;
#pragma unroll
        for (int k = 0; k < 8; ++k) tsum += v[k];
        int x = tsum;
#pragma unroll
        for (int d = 1; d < 64; d <<= 1) {
            int y = __shfl_up(x, d, 64);
            if (lane >= d) x += y;
        }
        if (lane == 63) wsum[wid] = x;
        __syncthreads();
        if (wid == 0) {
            int w = (lane < 16) ? wsum[lane] : 0;
            int xx = w;
#pragma unroll
            for (int d = 1; d < 16; d <<= 1) {
                int y = __shfl_up(xx, d, 64);
                if (lane >= d) xx += y;
            }
            if (lane < 16) wsum[lane] = xx - w;
            if (lane == 15) total_s = xx;
        }
        __syncthreads();
        int run = carry_s + wsum[wid] + (x - tsum);
        if (i0 + 8 <= n) {
            int o[8];
#pragma unroll
            for (int k = 0; k < 8; ++k) { o[k] = run; run += v[k]; }
            *reinterpret_cast<int4*>(off + i0)     = make_int4(o[0], o[1], o[2], o[3]);
            *reinterpret_cast<int4*>(off + i0 + 4) = make_int4(o[4], o[5], o[6], o[7]);
        } else {
#pragma unroll
            for (int k = 0; k < 8; ++k) if (i0 + k < n) { off[i0 + k] = run; run += v[k]; }
        }
        __syncthreads();
        if (t == 0) carry_s += total_s;
        __syncthreads();
    }
    if (t == 0) off[n] = carry_s;
}

static __global__ __launch_bounds__(1024)
void scan4_kernel(const int* c0, int* o0, int n0,
                  const int* c1, int* o1, int n1,
                  const int* c2, int* o2, int n2,
                  const int* c3, int* o3, int n3) {
    if (blockIdx.x == 0) scan_body(c0, o0, n0);
    else if (blockIdx.x == 1) scan_body(c1, o1, n1);
    else if (blockIdx.x == 2) scan_body(c2, o2, n2);
    else scan_body(c3, o3, n3);
}

// ---------------- CSR build phase 2: atomic-free scatter ----------------

struct SSeg { const int* srce; const int* dste; const int* pos; const int* rep; const int* off; int* eid; int ne, nd; };

static __device__ void scatter_body(const SSeg& s, int i) {
    int row = i / CHUNK;
    int d = s.dste[i];
    s.eid[s.off[d] + s.rep[(size_t)row * s.nd + d] + s.pos[i]] = s.srce[i];
}

static __global__ __launch_bounds__(256)
void scatter4_kernel(SSeg a, SSeg b, SSeg c, SSeg d) {
    int i = blockIdx.x * 256 + threadIdx.x;
    if (i < a.ne) { scatter_body(a, i); return; }
    i -= a.ne;
    if (i < b.ne) { scatter_body(b, i); return; }
    i -= b.ne;
    if (i < c.ne) { scatter_body(c, i); return; }
    i -= c.ne;
    if (i < d.ne) { scatter_body(d, i); }
}

// ---------------- dense GEMM: out[n,128] = opt_relu((X * rs) @ W + bias) ----------------
// RH: X is fp16 (row = 128 halves); WH: out written fp16. LDS/W/accum stay fp32.

template<int RELU, int RH, int WH>
static __global__ __launch_bounds__(256)
void gemm_kernel(const void* __restrict__ Xv, const float* __restrict__ rs,
                 const float* __restrict__ W, const float* __restrict__ bias,
                 void* __restrict__ outv, int n) {
    __shared__ float xs[32][128];
    const int r0 = blockIdx.x * 32;
    const int t = threadIdx.x;
    for (int i = t; i < 1024; i += 256) {
        int r = i >> 5;
        int c4 = i & 31;
        int row = r0 + r;
        float4 v = make_float4(0.f, 0.f, 0.f, 0.f);
        if (row < n) {
            if (RH) {
                float2 pk = reinterpret_cast<const float2*>(Xv)[row * 32 + c4];
                float2 lo = __half22float2(*reinterpret_cast<__half2*>(&pk.x));
                float2 hi = __half22float2(*reinterpret_cast<__half2*>(&pk.y));
                v = make_float4(lo.x, lo.y, hi.x, hi.y);
            } else {
                v = reinterpret_cast<const float4*>(Xv)[row * 32 + c4];
            }
            if (rs) { float s = rs[row]; v.x *= s; v.y *= s; v.z *= s; v.w *= s; }
        }
        reinterpret_cast<float4*>(&xs[r][0])[c4] = v;
    }
    __syncthreads();
    const int tx = t & 31, ty = t >> 5;
    const int c0 = tx << 2;
    float acc[4][4] = {};
    const float* wp = W + c0;
    for (int k = 0; k < 128; k += 4) {
        float4 w0 = *reinterpret_cast<const float4*>(wp + (k + 0) * 128);
        float4 w1 = *reinterpret_cast<const float4*>(wp + (k + 1) * 128);
        float4 w2 = *reinterpret_cast<const float4*>(wp + (k + 2) * 128);
        float4 w3 = *reinterpret_cast<const float4*>(wp + (k + 3) * 128);
#pragma unroll
        for (int i = 0; i < 4; ++i) {
            float4 xv = *reinterpret_cast<const float4*>(&xs[ty * 4 + i][k]);
            acc[i][0] += xv.x * w0.x; acc[i][1] += xv.x * w0.y; acc[i][2] += xv.x * w0.z; acc[i][3] += xv.x * w0.w;
            acc[i][0] += xv.y * w1.x; acc[i][1] += xv.y * w1.y; acc[i][2] += xv.y * w1.z; acc[i][3] += xv.y * w1.w;
            acc[i][0] += xv.z * w2.x; acc[i][1] += xv.z * w2.y; acc[i][2] += xv.z * w2.z; acc[i][3] += xv.z * w2.w;
            acc[i][0] += xv.w * w3.x; acc[i][1] += xv.w * w3.y; acc[i][2] += xv.w * w3.z; acc[i][3] += xv.w * w3.w;
        }
    }
    float4 bv = make_float4(0.f, 0.f, 0.f, 0.f);
    if (bias) bv = reinterpret_cast<const float4*>(bias)[tx];
#pragma unroll
    for (int i = 0; i < 4; ++i) {
        int row = r0 + ty * 4 + i;
        if (row < n) {
            float4 o;
            o.x = acc[i][0] + bv.x; o.y = acc[i][1] + bv.y;
            o.z = acc[i][2] + bv.z; o.w = acc[i][3] + bv.w;
            if (RELU) {
                o.x = fmaxf(o.x, 0.f); o.y = fmaxf(o.y, 0.f);
                o.z = fmaxf(o.z, 0.f); o.w = fmaxf(o.w, 0.f);
            }
            if (WH) {
                float2 pk;
                *reinterpret_cast<__half2*>(&pk.x) = __floats2half2_rn(o.x, o.y);
                *reinterpret_cast<__half2*>(&pk.y) = __floats2half2_rn(o.z, o.w);
                reinterpret_cast<float2*>(outv)[row * 32 + tx] = pk;
            } else {
                reinterpret_cast<float4*>(outv)[row * 32 + tx] = o;
            }
        }
    }
}

// ---------------- CSR aggregation, fp16 gather ----------------
// Gathers __half2 rows (2 cols/lane, 256B/row). Accum fp32.
// MODE 0: out = sum(h*pre)  -> fp32         (pre optional)
// MODE 1: out = relu(si*sum+b)*post         (OUTH: fp16 or fp32; post optional)
// MODE 2: out += relu(si*sum+b)             (OUTH fp16 RMW or fp32 RMW)

template<int MODE, int OUTH>
static __global__ __launch_bounds__(256)
void agg_kernel(const __half2* __restrict__ h2, const float* __restrict__ pre,
                const int* __restrict__ off, const int* __restrict__ eid,
                const float* __restrict__ si, const float* __restrict__ bias,
                const float* __restrict__ post,
                void* __restrict__ outv, int n_dst) {
    int row = blockIdx.x * 4 + (threadIdx.x >> 6);
    if (row >= n_dst) return;
    int lane = threadIdx.x & 63;
    int e0 = off[row], e1 = off[row + 1];
    float ax = 0.f, ay = 0.f;
    int j = e0;
    for (; j + 8 <= e1; j += 8) {
        int s[8];
#pragma unroll
        for (int k = 0; k < 8; ++k) s[k] = eid[j + k];
        float2 f[8];
#pragma unroll
        for (int k = 0; k < 8; ++k) f[k] = __half22float2(h2[(size_t)s[k] * 64 + lane]);
        if (pre) {
#pragma unroll
            for (int k = 0; k < 8; ++k) { float p = pre[s[k]]; ax += f[k].x * p; ay += f[k].y * p; }
        } else {
#pragma unroll
            for (int k = 0; k < 8; ++k) { ax += f[k].x; ay += f[k].y; }
        }
    }
    for (; j < e1; ++j) {
        int s = eid[j];
        float2 f = __half22float2(h2[(size_t)s * 64 + lane]);
        float p = pre ? pre[s] : 1.0f;
        ax += f.x * p; ay += f.y * p;
    }
    int oidx = row * 64 + lane;
    if (MODE == 0) {
        reinterpret_cast<float2*>(outv)[oidx] = make_float2(ax, ay);
    } else {
        float s = si[row];
        float2 b = reinterpret_cast<const float2*>(bias)[lane];
        float ox = fmaxf(ax * s + b.x, 0.f);
        float oy = fmaxf(ay * s + b.y, 0.f);
        if (MODE == 1 && post) { float pm = post[row]; ox *= pm; oy *= pm; }
        if (OUTH) {
            __half2* o = reinterpret_cast<__half2*>(outv) + oidx;
            if (MODE == 2) { float2 cur = __half22float2(*o); ox += cur.x; oy += cur.y; }
            *o = __floats2half2_rn(ox, oy);
        } else {
            float2* o = reinterpret_cast<float2*>(outv) + oidx;
            if (MODE == 2) { float2 cur = *o; ox += cur.x; oy += cur.y; }
            *o = make_float2(ox, oy);
        }
    }
}

// ---------------- orchestration ----------------

extern "C" void kernel_launch(void* const* d_in, const int* in_sizes, int n_in,
                              void* d_out, int out_size, void* d_ws, size_t ws_size,
                              hipStream_t stream) {
    const float* x_cell   = (const float*)d_in[1];
    const float* x_gotem  = (const float*)d_in[2];
    const float* W_eg_c2g = (const float*)d_in[3];  const float* b_eg_c2g = (const float*)d_in[4];
    const float* W_eg_t2g = (const float*)d_in[5];  const float* b_eg_t2g = (const float*)d_in[6];
    const float* W1_g2c   = (const float*)d_in[11]; const float* b1_g2c   = (const float*)d_in[12];
    const float* W1_g2t   = (const float*)d_in[15]; const float* b1_g2t   = (const float*)d_in[16];
    const float* W2_c2g   = (const float*)d_in[21]; const float* b2_c2g   = (const float*)d_in[22];
    const float* W2_t2g   = (const float*)d_in[25]; const float* b2_t2g   = (const float*)d_in[26];
    const float* W3_g2c   = (const float*)d_in[27]; const float* b3_g2c   = (const float*)d_in[28];
    const float* Wd_cell  = (const float*)d_in[29]; const float* bd_cell  = (const float*)d_in[30];
    const int* eg2c_src = (const int*)d_in[31]; const int* eg2c_dst = (const int*)d_in[32];
    const int* ec2g_src = (const int*)d_in[33]; const int* ec2g_dst = (const int*)d_in[34];
    const int* eg2t_src = (const int*)d_in[35]; const int* eg2t_dst = (const int*)d_in[36];
    const int* et2g_src = (const int*)d_in[37]; const int* et2g_dst = (const int*)d_in[38];

    char* p = (char*)d_ws;
    auto alloc = [&](size_t bytes) { char* r = p; p += (bytes + 255) & ~(size_t)255; return r; };
    float* h_buf = (float*)alloc((size_t)NC * 128 * 4);   // fp32 MODE0 outputs / fp16 gemm outputs (scratch)
    void*  g_buf = (void*)alloc((size_t)NG * 128 * 2);    // fp16 g / g2
    void*  c_buf = (void*)alloc((size_t)NC * 128 * 4);    // fp16 c1, later fp32 c3
    float* t_buf = (float*)alloc((size_t)NT * 128 * 4);   // fp32 t1 (never gathered)
    void*  xch   = (void*)alloc((size_t)NC * 128 * 2);    // fp16 x_cell * so_ec2g
    int* off_gc = (int*)alloc((NG + 1) * 4);  int* eid_gc = (int*)alloc((size_t)EGC * 4); // ec2g (dst=gene)
    int* off_gt = (int*)alloc((NG + 1) * 4);  int* eid_gt = (int*)alloc((size_t)EGT * 4); // et2g (dst=gene)
    int* off_c  = (int*)alloc((NC + 1) * 4);  int* eid_c  = (int*)alloc((size_t)EGC * 4); // eg2c (dst=cell)
    int* off_t  = (int*)alloc((NT + 1) * 4);  int* eid_t  = (int*)alloc((size_t)EGT * 4); // eg2t (dst=gotem)
    float* so_ec2g = (float*)alloc(NC * 4);
    float* so_et2g = (float*)alloc(NT * 4);
    float* so_eg2c = (float*)alloc(NG * 4);
    float* so_eg2t = (float*)alloc(NG * 4);
    float* si_ec2g = (float*)alloc(NG * 4);
    float* si_et2g = (float*)alloc(NG * 4);
    float* si_eg2c = (float*)alloc(NC * 4);
    float* si_eg2t = (float*)alloc(NT * 4);
    int* ct_a = (int*)alloc(NG * 4);
    int* ct_b = (int*)alloc(NG * 4);
    int* ct_c = (int*)alloc(NC * 4);
    int* ct_d = (int*)alloc(NT * 4);
    int* pos_a = (int*)alloc((size_t)EGC * 4);
    int* pos_b = (int*)alloc((size_t)EGT * 4);
    int* pos_c = (int*)alloc((size_t)EGC * 4);
    int* pos_d = (int*)alloc((size_t)EGT * 4);
    int* rd_a = (int*)alloc((size_t)24 * NG * 4);
    int* rd_b = (int*)alloc((size_t)8  * NG * 4);
    int* rd_c = (int*)alloc((size_t)24 * NC * 4);
    int* rd_d = (int*)alloc((size_t)8  * NT * 4);
    int* rs_a = (int*)alloc((size_t)24 * NC * 4);
    int* rs_b = (int*)alloc((size_t)8  * NT * 4);
    int* rs_c = (int*)alloc((size_t)24 * NG * 4);
    int* rs_d = (int*)alloc((size_t)8  * NG * 4);

    auto cdiv = [](int a, int b) { return (a + b - 1) / b; };
    const int ETOT = 2 * EGC + 2 * EGT;

    // ---- phase 1: LDS histograms ----
    HTab tab;
    tab.s[0]  = {ec2g_dst, rd_a, pos_a, EGC, 24, 10000, 2, NG};
    tab.s[1]  = {et2g_dst, rd_b, pos_b, EGT,  8, 10000, 2, NG};
    tab.s[2]  = {eg2c_dst, rd_c, pos_c, EGC, 24, 12500, 4, NC};
    tab.s[3]  = {eg2t_dst, rd_d, pos_d, EGT,  8,  8000, 1, NT};
    tab.s[4]  = {ec2g_src, rs_a, nullptr, EGC, 24, 12500, 4, NC};
    tab.s[5]  = {et2g_src, rs_b, nullptr, EGT,  8,  8000, 1, NT};
    tab.s[6]  = {eg2c_src, rs_c, nullptr, EGC, 24, 10000, 2, NG};
    tab.s[7]  = {eg2t_src, rs_d, nullptr, EGT,  8, 10000, 2, NG};
    tab.s[8] = tab.s[9] = tab.s[10] = tab.s[11] = HSeg{nullptr, nullptr, nullptr, 0, 0, 1, 0, 0};
    int hist_blocks = 24*2 + 8*2 + 24*4 + 8*1 + 24*4 + 8*1 + 24*2 + 8*2;  // 336
    hist_lds_kernel<<<hist_blocks, 1024, 0, stream>>>(tab);

    // ---- scales + replica prefix ----
    SPSeg sa{rd_a, rs_a, so_ec2g, si_ec2g, ct_a, NC, NG, 24, NC};
    SPSeg sb{rd_b, rs_b, so_et2g, si_et2g, ct_b, NT, NG,  8, NG};
    SPSeg sc{rd_c, rs_c, so_eg2c, si_eg2c, ct_c, NG, NC, 24, NC};
    SPSeg sd{rd_d, rs_d, so_eg2t, si_eg2t, ct_d, NG, NT,  8, NG};
    spscales4_kernel<<<cdiv(NC + NG + NC + NG, 256), 256, 0, stream>>>(sa, sb, sc, sd);

    // x_cell -> fp16 with folded so_ec2g (needs so; independent of scan/scatter)
    xconv_kernel<<<cdiv(NC * 32, 256), 256, 0, stream>>>(x_cell, so_ec2g, (float2*)xch);

    scan4_kernel<<<4, 1024, 0, stream>>>(ct_a, off_gc, NG, ct_b, off_gt, NG,
                                         ct_c, off_c, NC, ct_d, off_t, NT);

    // ---- phase 2: atomic-free scatter ----
    SSeg ba{ec2g_src, ec2g_dst, pos_a, rd_a, off_gc, eid_gc, EGC, NG};
    SSeg bb{et2g_src, et2g_dst, pos_b, rd_b, off_gt, eid_gt, EGT, NG};
    SSeg bc{eg2c_src, eg2c_dst, pos_c, rd_c, off_c,  eid_c,  EGC, NC};
    SSeg bd{eg2t_src, eg2t_dst, pos_d, rd_d, off_t,  eid_t,  EGT, NT};
    scatter4_kernel<<<cdiv(ETOT, 256), 256, 0, stream>>>(ba, bb, bc, bd);

    // ---- Layer E: g = relu(gconv(x_cell via ec2g) + gconv(x_gotem via et2g)) ----
    agg_kernel<0,0><<<cdiv(NG, 4), 256, 0, stream>>>((const __half2*)xch, nullptr, off_gc, eid_gc, nullptr, nullptr, nullptr, h_buf, NG);
    gemm_kernel<1,0,1><<<cdiv(NG, 32), 256, 0, stream>>>(h_buf, si_ec2g, W_eg_c2g, b_eg_c2g, g_buf, NG);
    gemm_kernel<0,0,1><<<cdiv(NT, 32), 256, 0, stream>>>(x_gotem, so_et2g, W_eg_t2g, nullptr, h_buf, NT);
    agg_kernel<2,1><<<cdiv(NG, 4), 256, 0, stream>>>((const __half2*)h_buf, nullptr, off_gt, eid_gt, si_et2g, b_eg_t2g, nullptr, g_buf, NG);

    // ---- c1 = gconv(g via eg2c), post-scale fold so_ec2g ----
    gemm_kernel<0,1,1><<<cdiv(NG, 32), 256, 0, stream>>>(g_buf, so_eg2c, W1_g2c, nullptr, h_buf, NG);
    agg_kernel<1,1><<<cdiv(NC, 4), 256, 0, stream>>>((const __half2*)h_buf, nullptr, off_c, eid_c, si_eg2c, b1_g2c, so_ec2g, c_buf, NC);

    // ---- t1 = gconv(g via eg2t): agg-first (t1 never gathered -> fp32) ----
    agg_kernel<0,0><<<cdiv(NT, 4), 256, 0, stream>>>((const __half2*)g_buf, so_eg2t, off_t, eid_t, nullptr, nullptr, nullptr, h_buf, NT);
    gemm_kernel<1,0,0><<<cdiv(NT, 32), 256, 0, stream>>>(h_buf, si_eg2t, W1_g2t, b1_g2t, t_buf, NT);

    // ---- g2 = gconv(c1 via ec2g) + gconv(t1 via et2g) ----
    agg_kernel<0,0><<<cdiv(NG, 4), 256, 0, stream>>>((const __half2*)c_buf, nullptr, off_gc, eid_gc, nullptr, nullptr, nullptr, h_buf, NG);
    gemm_kernel<1,0,1><<<cdiv(NG, 32), 256, 0, stream>>>(h_buf, si_ec2g, W2_c2g, b2_c2g, g_buf, NG);
    gemm_kernel<0,0,1><<<cdiv(NT, 32), 256, 0, stream>>>(t_buf, so_et2g, W2_t2g, nullptr, h_buf, NT);
    agg_kernel<2,1><<<cdiv(NG, 4), 256, 0, stream>>>((const __half2*)h_buf, nullptr, off_gt, eid_gt, si_et2g, b2_t2g, nullptr, g_buf, NG);

    // ---- c3 = gconv(g2 via eg2c) -> fp32 ----
    gemm_kernel<0,1,1><<<cdiv(NG, 32), 256, 0, stream>>>(g_buf, so_eg2c, W3_g2c, nullptr, h_buf, NG);
    agg_kernel<1,0><<<cdiv(NC, 4), 256, 0, stream>>>((const __half2*)h_buf, nullptr, off_c, eid_c, si_eg2c, b3_g2c, nullptr, c_buf, NC);

    // ---- out = c3 @ Wd_cell + bd_cell ----
    gemm_kernel<0,0,0><<<cdiv(NC, 32), 256, 0, stream>>>(c_buf, nullptr, Wd_cell, bd_cell, d_out, NC);
}

// Round 9
// 492.926 us; speedup vs baseline: 1.8073x; 1.1500x over previous
//
#include <hip/hip_runtime.h>
#include <hip/hip_fp16.h>

#define NG 20000
#define NC 50000
#define NT 8000
#define EGC 600000
#define EGT 200000
#define CHUNK 25000

typedef _Float16 h8 __attribute__((ext_vector_type(8)));
typedef float f4 __attribute__((ext_vector_type(4)));

// ---------------- CSR build phase 1: LDS-privatized histograms ----------------

struct HSeg { const int* idx; int* rep; int* pos; int ne, nb, bpr, nranges, nd; };
struct HTab { HSeg s[12]; };

static __global__ __launch_bounds__(1024)
void hist_lds_kernel(HTab tab) {
    __shared__ int h[12800];
    int b = blockIdx.x, sidx = 0;
    for (;;) {
        int nbl = tab.s[sidx].nb * tab.s[sidx].nranges;
        if (b < nbl) break;
        b -= nbl; ++sidx;
    }
    const HSeg g = tab.s[sidx];
    const int row = b % g.nb, range = b / g.nb;
    const int lo = range * g.bpr;
    const int hi = min(lo + g.bpr, g.nd);
    const int nbins = hi - lo;
    for (int i = threadIdx.x; i < nbins; i += 1024) h[i] = 0;
    __syncthreads();
    const int e0 = row * CHUNK;
    const int e1 = min(e0 + CHUNK, g.ne);
    if (g.pos) {
        for (int i = e0 + (int)threadIdx.x; i < e1; i += 1024) {
            int d = g.idx[i];
            if (d >= lo && d < hi) {
                int p = atomicAdd(&h[d - lo], 1);
                g.pos[i] = p;
            }
        }
    } else {
        for (int i = e0 + (int)threadIdx.x; i < e1; i += 1024) {
            int d = g.idx[i];
            if (d >= lo && d < hi) atomicAdd(&h[d - lo], 1);
        }
    }
    __syncthreads();
    int* rp = g.rep + (size_t)row * g.nd + lo;
    for (int i = threadIdx.x; i < nbins; i += 1024) rp[i] = h[i];
}

// ---------------- scales + replica prefix ----------------

struct SPSeg { int* repd; const int* reps; float* so; float* si; int* ci_tot; int ns, nd, nb, len; };

static __device__ void sp_body(const SPSeg& s, int i) {
    if (i < s.ns) {
        int c = 0;
        for (int r = 0; r < s.nb; ++r) c += s.reps[(size_t)r * s.ns + i];
        if (c < 1) c = 1;
        s.so[i] = 1.0f / sqrtf((float)c);
    }
    if (i < s.nd) {
        int run = 0;
        for (int r = 0; r < s.nb; ++r) {
            int* p = s.repd + (size_t)r * s.nd + i;
            int t = *p; *p = run; run += t;
        }
        s.ci_tot[i] = run;
        int c = run < 1 ? 1 : run;
        s.si[i] = 1.0f / sqrtf((float)c);
    }
}

static __global__ __launch_bounds__(256)
void spscales4_kernel(SPSeg a, SPSeg b, SPSeg c, SPSeg d) {
    int i = blockIdx.x * 256 + threadIdx.x;
    if (i < a.len) { sp_body(a, i); return; }
    i -= a.len;
    if (i < b.len) { sp_body(b, i); return; }
    i -= b.len;
    if (i < c.len) { sp_body(c, i); return; }
    i -= c.len;
    if (i < d.len) { sp_body(d, i); }
}

// ---------------- fp32 -> fp16 convert with optional per-row scale fold ----------------

static __global__ __launch_bounds__(256)
void xconv_kernel(const float* __restrict__ x, const float* __restrict__ so,
                  float2* __restrict__ out, int ngran) {   // ngran = n*32 (float4 granules)
    int i = blockIdx.x * 256 + threadIdx.x;
    if (i >= ngran) return;
    int row = i >> 5;
    float s = so ? so[row] : 1.0f;
    float4 v = reinterpret_cast<const float4*>(x)[i];
    float2 pk;
    *reinterpret_cast<__half2*>(&pk.x) = __floats2half2_rn(v.x * s, v.y * s);
    *reinterpret_cast<__half2*>(&pk.y) = __floats2half2_rn(v.z * s, v.w * s);
    out[i] = pk;
}

// ---------------- weight pack: fp32 W[128][128] -> fp16 MFMA B-fragments ----------------
// Slot (ct,kk,lane,j) holds W[kk*32 + (lane>>4)*8 + j][ct*16 + (lane&15)].
// Same k-bijection (k = g*8+j) is used by the A-side load in gemm_mfma.

struct PackTab { const float* w[8]; };

static __global__ __launch_bounds__(256)
void pack_kernel(PackTab pt, _Float16* __restrict__ wp) {
    int wi = blockIdx.x >> 3;
    int t = ((blockIdx.x & 7) << 8) + threadIdx.x;   // 0..2047 = ct*256 + kk*64 + lane
    int lane = t & 63, kk = (t >> 6) & 3, ct = t >> 8;
    int g = lane >> 4, r = lane & 15;
    const float* W = pt.w[wi];
    int n = ct * 16 + r;
    int kbase = kk * 32 + g * 8;
    h8 v;
#pragma unroll
    for (int j = 0; j < 8; ++j) v[j] = (_Float16)W[(kbase + j) * 128 + n];
    *reinterpret_cast<h8*>(wp + (size_t)wi * 16384 + (size_t)t * 8) = v;
}

// ---------------- tiled block scan, VPT=8 ----------------

static __device__ void scan_body(const int* __restrict__ cnt, int* __restrict__ off, int n) {
    __shared__ int wsum[16];
    __shared__ int carry_s, total_s;
    const int t = threadIdx.x;
    const int lane = t & 63, wid = t >> 6;
    if (t == 0) carry_s = 0;
    __syncthreads();
    for (int base = 0; base < n; base += 8192) {
        int i0 = base + t * 8;
        int v[8];
        if (i0 + 8 <= n) {
            int4 a = *reinterpret_cast<const int4*>(cnt + i0);
            int4 b = *reinterpret_cast<const int4*>(cnt + i0 + 4);
            v[0]=a.x; v[1]=a.y; v[2]=a.z; v[3]=a.w; v[4]=b.x; v[5]=b.y; v[6]=b.z; v[7]=b.w;
        } else {
#pragma unroll
            for (int k = 0; k < 8; ++k) v[k] = (i0 + k < n) ? cnt[i0 + k] : 0;
        }
        int tsum = 0;
#pragma unroll
        for (int k = 0; k < 8; ++k) tsum += v[k];
        int x = tsum;
#pragma unroll
        for (int d = 1; d < 64; d <<= 1) {
            int y = __shfl_up(x, d, 64);
            if (lane >= d) x += y;
        }
        if (lane == 63) wsum[wid] = x;
        __syncthreads();
        if (wid == 0) {
            int w = (lane < 16) ? wsum[lane] : 0;
            int xx = w;
#pragma unroll
            for (int d = 1; d < 16; d <<= 1) {
                int y = __shfl_up(xx, d, 64);
                if (lane >= d) xx += y;
            }
            if (lane < 16) wsum[lane] = xx - w;
            if (lane == 15) total_s = xx;
        }
        __syncthreads();
        int run = carry_s + wsum[wid] + (x - tsum);
        if (i0 + 8 <= n) {
            int o[8];
#pragma unroll
            for (int k = 0; k < 8; ++k) { o[k] = run; run += v[k]; }
            *reinterpret_cast<int4*>(off + i0)     = make_int4(o[0], o[1], o[2], o[3]);
            *reinterpret_cast<int4*>(off + i0 + 4) = make_int4(o[4], o[5], o[6], o[7]);
        } else {
#pragma unroll
            for (int k = 0; k < 8; ++k) if (i0 + k < n) { off[i0 + k] = run; run += v[k]; }
        }
        __syncthreads();
        if (t == 0) carry_s += total_s;
        __syncthreads();
    }
    if (t == 0) off[n] = carry_s;
}

static __global__ __launch_bounds__(1024)
void scan4_kernel(const int* c0, int* o0, int n0,
                  const int* c1, int* o1, int n1,
                  const int* c2, int* o2, int n2,
                  const int* c3, int* o3, int n3) {
    if (blockIdx.x == 0) scan_body(c0, o0, n0);
    else if (blockIdx.x == 1) scan_body(c1, o1, n1);
    else if (blockIdx.x == 2) scan_body(c2, o2, n2);
    else scan_body(c3, o3, n3);
}

// ---------------- CSR build phase 2: atomic-free scatter ----------------

struct SSeg { const int* srce; const int* dste; const int* pos; const int* rep; const int* off; int* eid; int ne, nd; };

static __device__ void scatter_body(const SSeg& s, int i) {
    int row = i / CHUNK;
    int d = s.dste[i];
    s.eid[s.off[d] + s.rep[(size_t)row * s.nd + d] + s.pos[i]] = s.srce[i];
}

static __global__ __launch_bounds__(256)
void scatter4_kernel(SSeg a, SSeg b, SSeg c, SSeg d) {
    int i = blockIdx.x * 256 + threadIdx.x;
    if (i < a.ne) { scatter_body(a, i); return; }
    i -= a.ne;
    if (i < b.ne) { scatter_body(b, i); return; }
    i -= b.ne;
    if (i < c.ne) { scatter_body(c, i); return; }
    i -= c.ne;
    if (i < d.ne) { scatter_body(d, i); }
}

// ---------------- MFMA GEMM: out[n,128] = opt_relu(scale[row]*(X@W) + bias) ----------------
// X fp16 [n][128]; Wp packed fp16 fragments; acc fp32. 64 rows/block, 4 waves.
// WH: write fp16 (else fp32).

template<int RELU, int WH>
static __global__ __launch_bounds__(256)
void gemm_mfma(const _Float16* __restrict__ X, const float* __restrict__ scale,
               const _Float16* __restrict__ Wp, const float* __restrict__ bias,
               void* __restrict__ outv, int n) {
    const int wave = threadIdx.x >> 6, lane = threadIdx.x & 63;
    const int g = lane >> 4, r = lane & 15;
    const int r0 = blockIdx.x * 64 + wave * 16;
    const int arow = r0 + r;
    h8 a[4];
    if (arow < n) {
        const _Float16* xr = X + (size_t)arow * 128;
#pragma unroll
        for (int kk = 0; kk < 4; ++kk)
            a[kk] = *reinterpret_cast<const h8*>(xr + kk * 32 + g * 8);
    } else {
#pragma unroll
        for (int kk = 0; kk < 4; ++kk)
#pragma unroll
            for (int j = 0; j < 8; ++j) a[kk][j] = (_Float16)0.f;
    }
    int orow[4]; float sc[4];
#pragma unroll
    for (int reg = 0; reg < 4; ++reg) {
        orow[reg] = r0 + g * 4 + reg;
        sc[reg] = (scale && orow[reg] < n) ? scale[orow[reg]] : 1.0f;
    }
    const h8* bp = reinterpret_cast<const h8*>(Wp);
#pragma unroll
    for (int ct = 0; ct < 8; ++ct) {
        f4 acc = {0.f, 0.f, 0.f, 0.f};
#pragma unroll
        for (int kk = 0; kk < 4; ++kk)
            acc = __builtin_amdgcn_mfma_f32_16x16x32_f16(a[kk], bp[(ct * 4 + kk) * 64 + lane], acc, 0, 0, 0);
        float bx = bias ? bias[ct * 16 + r] : 0.f;
#pragma unroll
        for (int reg = 0; reg < 4; ++reg) {
            int row = orow[reg];
            if (row < n) {
                float o = acc[reg] * sc[reg] + bx;
                if (RELU) o = fmaxf(o, 0.f);
                if (WH) reinterpret_cast<_Float16*>(outv)[(size_t)row * 128 + ct * 16 + r] = (_Float16)o;
                else    reinterpret_cast<float*>(outv)[(size_t)row * 128 + ct * 16 + r] = o;
            }
        }
    }
}

// ---------------- CSR aggregation, fp16 gather / fp16 out ----------------
// MODE 0: out = sum(h*pre) -> fp16          (pre optional)
// MODE 1: out = relu(si*sum+b)*post -> fp16 (post optional)
// MODE 2: out += relu(si*sum+b)   (fp16 RMW)

template<int MODE>
static __global__ __launch_bounds__(256)
void agg_kernel(const __half2* __restrict__ h2, const float* __restrict__ pre,
                const int* __restrict__ off, const int* __restrict__ eid,
                const float* __restrict__ si, const float* __restrict__ bias,
                const float* __restrict__ post,
                __half2* __restrict__ out, int n_dst) {
    int row = blockIdx.x * 4 + (threadIdx.x >> 6);
    if (row >= n_dst) return;
    int lane = threadIdx.x & 63;
    int e0 = off[row], e1 = off[row + 1];
    float ax = 0.f, ay = 0.f;
    int j = e0;
    for (; j + 8 <= e1; j += 8) {
        int s[8];
#pragma unroll
        for (int k = 0; k < 8; ++k) s[k] = eid[j + k];
        float2 f[8];
#pragma unroll
        for (int k = 0; k < 8; ++k) f[k] = __half22float2(h2[(size_t)s[k] * 64 + lane]);
        if (pre) {
#pragma unroll
            for (int k = 0; k < 8; ++k) { float p = pre[s[k]]; ax += f[k].x * p; ay += f[k].y * p; }
        } else {
#pragma unroll
            for (int k = 0; k < 8; ++k) { ax += f[k].x; ay += f[k].y; }
        }
    }
    for (; j < e1; ++j) {
        int s = eid[j];
        float2 f = __half22float2(h2[(size_t)s * 64 + lane]);
        float p = pre ? pre[s] : 1.0f;
        ax += f.x * p; ay += f.y * p;
    }
    __half2* o = out + (size_t)row * 64 + lane;
    if (MODE == 0) {
        *o = __floats2half2_rn(ax, ay);
    } else {
        float s = si[row];
        float2 b = reinterpret_cast<const float2*>(bias)[lane];
        float ox = fmaxf(ax * s + b.x, 0.f);
        float oy = fmaxf(ay * s + b.y, 0.f);
        if (MODE == 1 && post) { float pm = post[row]; ox *= pm; oy *= pm; }
        if (MODE == 2) { float2 cur = __half22float2(*o); ox += cur.x; oy += cur.y; }
        *o = __floats2half2_rn(ox, oy);
    }
}

// ---------------- orchestration ----------------

extern "C" void kernel_launch(void* const* d_in, const int* in_sizes, int n_in,
                              void* d_out, int out_size, void* d_ws, size_t ws_size,
                              hipStream_t stream) {
    const float* x_cell   = (const float*)d_in[1];
    const float* x_gotem  = (const float*)d_in[2];
    const float* W_eg_c2g = (const float*)d_in[3];  const float* b_eg_c2g = (const float*)d_in[4];
    const float* W_eg_t2g = (const float*)d_in[5];  const float* b_eg_t2g = (const float*)d_in[6];
    const float* W1_g2c   = (const float*)d_in[11]; const float* b1_g2c   = (const float*)d_in[12];
    const float* W1_g2t   = (const float*)d_in[15]; const float* b1_g2t   = (const float*)d_in[16];
    const float* W2_c2g   = (const float*)d_in[21]; const float* b2_c2g   = (const float*)d_in[22];
    const float* W2_t2g   = (const float*)d_in[25]; const float* b2_t2g   = (const float*)d_in[26];
    const float* W3_g2c   = (const float*)d_in[27]; const float* b3_g2c   = (const float*)d_in[28];
    const float* Wd_cell  = (const float*)d_in[29]; const float* bd_cell  = (const float*)d_in[30];
    const int* eg2c_src = (const int*)d_in[31]; const int* eg2c_dst = (const int*)d_in[32];
    const int* ec2g_src = (const int*)d_in[33]; const int* ec2g_dst = (const int*)d_in[34];
    const int* eg2t_src = (const int*)d_in[35]; const int* eg2t_dst = (const int*)d_in[36];
    const int* et2g_src = (const int*)d_in[37]; const int* et2g_dst = (const int*)d_in[38];

    char* p = (char*)d_ws;
    auto alloc = [&](size_t bytes) { char* r = p; p += (bytes + 255) & ~(size_t)255; return r; };
    _Float16* h16 = (_Float16*)alloc((size_t)NG * 128 * 2);   // gemm-input staging (<=NG rows)
    _Float16* g16 = (_Float16*)alloc((size_t)NG * 128 * 2);   // g, then g2
    _Float16* c16 = (_Float16*)alloc((size_t)NC * 128 * 2);   // c1, then c3
    _Float16* t16 = (_Float16*)alloc((size_t)NT * 128 * 2);   // t1
    _Float16* xch = (_Float16*)alloc((size_t)NC * 128 * 2);   // x_cell * so_ec2g
    _Float16* xgh = (_Float16*)alloc((size_t)NT * 128 * 2);   // x_gotem
    _Float16* wpk = (_Float16*)alloc((size_t)8 * 16384 * 2);  // 8 packed weights
    int* off_gc = (int*)alloc((NG + 1) * 4);  int* eid_gc = (int*)alloc((size_t)EGC * 4);
    int* off_gt = (int*)alloc((NG + 1) * 4);  int* eid_gt = (int*)alloc((size_t)EGT * 4);
    int* off_c  = (int*)alloc((NC + 1) * 4);  int* eid_c  = (int*)alloc((size_t)EGC * 4);
    int* off_t  = (int*)alloc((NT + 1) * 4);  int* eid_t  = (int*)alloc((size_t)EGT * 4);
    float* so_ec2g = (float*)alloc(NC * 4);
    float* so_et2g = (float*)alloc(NT * 4);
    float* so_eg2c = (float*)alloc(NG * 4);
    float* so_eg2t = (float*)alloc(NG * 4);
    float* si_ec2g = (float*)alloc(NG * 4);
    float* si_et2g = (float*)alloc(NG * 4);
    float* si_eg2c = (float*)alloc(NC * 4);
    float* si_eg2t = (float*)alloc(NT * 4);
    int* ct_a = (int*)alloc(NG * 4);
    int* ct_b = (int*)alloc(NG * 4);
    int* ct_c = (int*)alloc(NC * 4);
    int* ct_d = (int*)alloc(NT * 4);
    int* pos_a = (int*)alloc((size_t)EGC * 4);
    int* pos_b = (int*)alloc((size_t)EGT * 4);
    int* pos_c = (int*)alloc((size_t)EGC * 4);
    int* pos_d = (int*)alloc((size_t)EGT * 4);
    int* rd_a = (int*)alloc((size_t)24 * NG * 4);
    int* rd_b = (int*)alloc((size_t)8  * NG * 4);
    int* rd_c = (int*)alloc((size_t)24 * NC * 4);
    int* rd_d = (int*)alloc((size_t)8  * NT * 4);
    int* rs_a = (int*)alloc((size_t)24 * NC * 4);
    int* rs_b = (int*)alloc((size_t)8  * NT * 4);
    int* rs_c = (int*)alloc((size_t)24 * NG * 4);
    int* rs_d = (int*)alloc((size_t)8  * NG * 4);

    auto cdiv = [](int a, int b) { return (a + b - 1) / b; };
    const int ETOT = 2 * EGC + 2 * EGT;

    // ---- weight pack (independent of everything else) ----
    PackTab pt;
    pt.w[0] = W_eg_c2g; pt.w[1] = W_eg_t2g; pt.w[2] = W1_g2c; pt.w[3] = W1_g2t;
    pt.w[4] = W2_c2g;   pt.w[5] = W2_t2g;   pt.w[6] = W3_g2c; pt.w[7] = Wd_cell;
    pack_kernel<<<64, 256, 0, stream>>>(pt, wpk);
    _Float16* Wp_egc = wpk + 0 * 16384; _Float16* Wp_egt = wpk + 1 * 16384;
    _Float16* Wp_1gc = wpk + 2 * 16384; _Float16* Wp_1gt = wpk + 3 * 16384;
    _Float16* Wp_2cg = wpk + 4 * 16384; _Float16* Wp_2tg = wpk + 5 * 16384;
    _Float16* Wp_3gc = wpk + 6 * 16384; _Float16* Wp_d   = wpk + 7 * 16384;

    // ---- phase 1: LDS histograms ----
    HTab tab;
    tab.s[0]  = {ec2g_dst, rd_a, pos_a, EGC, 24, 10000, 2, NG};
    tab.s[1]  = {et2g_dst, rd_b, pos_b, EGT,  8, 10000, 2, NG};
    tab.s[2]  = {eg2c_dst, rd_c, pos_c, EGC, 24, 12500, 4, NC};
    tab.s[3]  = {eg2t_dst, rd_d, pos_d, EGT,  8,  8000, 1, NT};
    tab.s[4]  = {ec2g_src, rs_a, nullptr, EGC, 24, 12500, 4, NC};
    tab.s[5]  = {et2g_src, rs_b, nullptr, EGT,  8,  8000, 1, NT};
    tab.s[6]  = {eg2c_src, rs_c, nullptr, EGC, 24, 10000, 2, NG};
    tab.s[7]  = {eg2t_src, rs_d, nullptr, EGT,  8, 10000, 2, NG};
    tab.s[8] = tab.s[9] = tab.s[10] = tab.s[11] = HSeg{nullptr, nullptr, nullptr, 0, 0, 1, 0, 0};
    int hist_blocks = 24*2 + 8*2 + 24*4 + 8*1 + 24*4 + 8*1 + 24*2 + 8*2;  // 336
    hist_lds_kernel<<<hist_blocks, 1024, 0, stream>>>(tab);

    // ---- scales + replica prefix ----
    SPSeg sa{rd_a, rs_a, so_ec2g, si_ec2g, ct_a, NC, NG, 24, NC};
    SPSeg sb{rd_b, rs_b, so_et2g, si_et2g, ct_b, NT, NG,  8, NG};
    SPSeg sc{rd_c, rs_c, so_eg2c, si_eg2c, ct_c, NG, NC, 24, NC};
    SPSeg sd{rd_d, rs_d, so_eg2t, si_eg2t, ct_d, NG, NT,  8, NG};
    spscales4_kernel<<<cdiv(NC + NG + NC + NG, 256), 256, 0, stream>>>(sa, sb, sc, sd);

    // fp16 conversions (x_cell pre-scaled by so_ec2g; x_gotem plain)
    xconv_kernel<<<cdiv(NC * 32, 256), 256, 0, stream>>>(x_cell, so_ec2g, (float2*)xch, NC * 32);
    xconv_kernel<<<cdiv(NT * 32, 256), 256, 0, stream>>>(x_gotem, nullptr, (float2*)xgh, NT * 32);

    scan4_kernel<<<4, 1024, 0, stream>>>(ct_a, off_gc, NG, ct_b, off_gt, NG,
                                         ct_c, off_c, NC, ct_d, off_t, NT);

    // ---- phase 2: atomic-free scatter ----
    SSeg ba{ec2g_src, ec2g_dst, pos_a, rd_a, off_gc, eid_gc, EGC, NG};
    SSeg bb{et2g_src, et2g_dst, pos_b, rd_b, off_gt, eid_gt, EGT, NG};
    SSeg bc{eg2c_src, eg2c_dst, pos_c, rd_c, off_c,  eid_c,  EGC, NC};
    SSeg bd{eg2t_src, eg2t_dst, pos_d, rd_d, off_t,  eid_t,  EGT, NT};
    scatter4_kernel<<<cdiv(ETOT, 256), 256, 0, stream>>>(ba, bb, bc, bd);

    // ---- Layer E: g = relu(gconv(x_cell via ec2g) + gconv(x_gotem via et2g)) ----
    agg_kernel<0><<<cdiv(NG, 4), 256, 0, stream>>>((const __half2*)xch, nullptr, off_gc, eid_gc, nullptr, nullptr, nullptr, (__half2*)h16, NG);
    gemm_mfma<1,1><<<cdiv(NG, 64), 256, 0, stream>>>(h16, si_ec2g, Wp_egc, b_eg_c2g, g16, NG);
    gemm_mfma<0,1><<<cdiv(NT, 64), 256, 0, stream>>>(xgh, so_et2g, Wp_egt, nullptr, h16, NT);
    agg_kernel<2><<<cdiv(NG, 4), 256, 0, stream>>>((const __half2*)h16, nullptr, off_gt, eid_gt, si_et2g, b_eg_t2g, nullptr, (__half2*)g16, NG);

    // ---- c1 = gconv(g via eg2c), post-scale fold so_ec2g ----
    gemm_mfma<0,1><<<cdiv(NG, 64), 256, 0, stream>>>(g16, so_eg2c, Wp_1gc, nullptr, h16, NG);
    agg_kernel<1><<<cdiv(NC, 4), 256, 0, stream>>>((const __half2*)h16, nullptr, off_c, eid_c, si_eg2c, b1_g2c, so_ec2g, (__half2*)c16, NC);

    // ---- t1 = gconv(g via eg2t): agg-first ----
    agg_kernel<0><<<cdiv(NT, 4), 256, 0, stream>>>((const __half2*)g16, so_eg2t, off_t, eid_t, nullptr, nullptr, nullptr, (__half2*)h16, NT);
    gemm_mfma<1,1><<<cdiv(NT, 64), 256, 0, stream>>>(h16, si_eg2t, Wp_1gt, b1_g2t, t16, NT);

    // ---- g2 = gconv(c1 via ec2g) + gconv(t1 via et2g) ----
    agg_kernel<0><<<cdiv(NG, 4), 256, 0, stream>>>((const __half2*)c16, nullptr, off_gc, eid_gc, nullptr, nullptr, nullptr, (__half2*)h16, NG);
    gemm_mfma<1,1><<<cdiv(NG, 64), 256, 0, stream>>>(h16, si_ec2g, Wp_2cg, b2_c2g, g16, NG);
    gemm_mfma<0,1><<<cdiv(NT, 64), 256, 0, stream>>>(t16, so_et2g, Wp_2tg, nullptr, h16, NT);
    agg_kernel<2><<<cdiv(NG, 4), 256, 0, stream>>>((const __half2*)h16, nullptr, off_gt, eid_gt, si_et2g, b2_t2g, nullptr, (__half2*)g16, NG);

    // ---- c3 = gconv(g2 via eg2c) ----
    gemm_mfma<0,1><<<cdiv(NG, 64), 256, 0, stream>>>(g16, so_eg2c, Wp_3gc, nullptr, h16, NG);
    agg_kernel<1><<<cdiv(NC, 4), 256, 0, stream>>>((const __half2*)h16, nullptr, off_c, eid_c, si_eg2c, b3_g2c, nullptr, (__half2*)c16, NC);

    // ---- out = c3 @ Wd_cell + bd_cell (fp32 out) ----
    gemm_mfma<0,0><<<cdiv(NC, 64), 256, 0, stream>>>(c16, nullptr, Wp_d, bd_cell, d_out, NC);
}